// Round 7
// baseline (306.308 us; speedup 1.0000x reference)
//
#include <hip/hip_runtime.h>
#include <math.h>

#define NTOT 65536
#define LCH 128
#define WRM 64
#define CCH 512          // NTOT / LCH
#define NB 128           // sort blocks
#define EPB 512          // elements per sort block

__device__ __forceinline__ float d_softplus(float x){
  return fmaxf(x, 0.f) + __logf(1.f + __expf(-fabsf(x)));
}
__device__ __forceinline__ float d_sigmoid(float x){
  return 1.f / (1.f + __expf(-x));
}
__device__ __forceinline__ float fast_rcp(float x){
  return __builtin_amdgcn_rcpf(x);
}
template<int CTRL>
__device__ __forceinline__ float dpp_mov(float x){
  return __int_as_float(__builtin_amdgcn_update_dpp(0, __float_as_int(x), CTRL, 0xF, 0xF, true));
}
// DPP ctrls: 0xB1 quad_perm xor1, 0x4E quad_perm xor2, 0x121 row_ror:1,
// 0x140 row_mirror, 0x141 row_half_mirror.

__device__ __forceinline__ unsigned block_incl_scan(unsigned v, unsigned* buf, int t){
  buf[t] = v; __syncthreads();
  #pragma unroll
  for (int off = 1; off < 256; off <<= 1){
    unsigned u = (t >= off) ? buf[t-off] : 0u;
    __syncthreads();
    buf[t] += u;
    __syncthreads();
  }
  unsigned r = buf[t];
  __syncthreads();
  return r;
}

// ============ hist0: pass-0 per-block 2048-bin hist + zero next hists ============
__global__ __launch_bounds__(256) void k_hist0(
    const float* __restrict__ g,
    unsigned* __restrict__ gh0, unsigned* __restrict__ gh1, unsigned* __restrict__ gh2)
{
  __shared__ unsigned h[2048];
  int t = threadIdx.x, blk = blockIdx.x;
  for (int k = t; k < 2048; k += 256) h[k] = 0u;
  __syncthreads();
  #pragma unroll
  for (int r = 0; r < 2; ++r){
    int i = blk*EPB + r*256 + t;
    unsigned key = __float_as_uint(g[i]) & 0x7fffffffu;
    atomicAdd(&h[key & 2047u], 1u);
  }
  __syncthreads();
  for (int k = t; k < 2048; k += 256) gh0[blk*2048 + k] = h[k];
  for (int k = t; k < 2048; k += 256) gh1[blk*2048 + k] = 0u;
  for (int k = t; k < 1024; k += 256) gh2[blk*1024 + k] = 0u;
}

// ============ scatter pass: redundant global prefix + stable ballot scatter ======
// Builds next pass's per-destination-block histogram on the fly.
template<int SHIFT, int NBITS, int NEXTSHIFT, int NEXTBITS, int LAST>
__global__ __launch_bounds__(256) void k_scat(
    const float* __restrict__ gsrc,
    const unsigned* __restrict__ keys_in, const unsigned* __restrict__ idx_in,
    unsigned* __restrict__ keys_out, unsigned* __restrict__ idx_out,
    const unsigned* __restrict__ ghist, unsigned* __restrict__ ghn,
    unsigned* __restrict__ unsrt)
{
  const int BINS = 1 << NBITS, BPT = BINS / 256;
  __shared__ unsigned runv[1 << NBITS];
  __shared__ unsigned shw[4 << NBITS];
  __shared__ unsigned buf[256];
  int t = threadIdx.x, blk = blockIdx.x, lane = t & 63, wv = t >> 6;
  unsigned tot[BPT], moff[BPT];
  #pragma unroll
  for (int k = 0; k < BPT; ++k){ tot[k] = 0u; moff[k] = 0u; }
  for (int b = 0; b < NB; ++b){
    #pragma unroll
    for (int k = 0; k < BPT; ++k){
      unsigned v = ghist[b*BINS + t*BPT + k];
      if (b < blk) moff[k] += v;
      tot[k] += v;
    }
  }
  unsigned s = 0;
  #pragma unroll
  for (int k = 0; k < BPT; ++k) s += tot[k];
  unsigned incl = block_incl_scan(s, buf, t);
  unsigned run = incl - s;
  #pragma unroll
  for (int k = 0; k < BPT; ++k){ runv[t*BPT + k] = run + moff[k]; run += tot[k]; }
  for (int k = t; k < 4*BINS; k += 256) shw[k] = 0u;
  __syncthreads();
  #pragma unroll
  for (int r = 0; r < 2; ++r){
    int i = blk*EPB + r*256 + t;
    unsigned key = (SHIFT == 0) ? (__float_as_uint(gsrc[i]) & 0x7fffffffu) : keys_in[i];
    unsigned id  = (SHIFT == 0) ? (unsigned)i : idx_in[i];
    unsigned dig = (key >> SHIFT) & (BINS - 1);
    unsigned long long m = ~0ull;
    #pragma unroll
    for (int b = 0; b < NBITS; ++b){
      unsigned long long bb = __ballot((dig >> b) & 1u);
      m &= ((dig >> b) & 1u) ? bb : ~bb;
    }
    unsigned rank = (unsigned)__popcll(m & ((1ull << lane) - 1ull));
    unsigned cnt  = (unsigned)__popcll(m);
    if (rank == 0) shw[wv*BINS + dig] = cnt;
    __syncthreads();
    unsigned pos = runv[dig] + rank;
    for (int w2 = 0; w2 < wv; ++w2) pos += shw[w2*BINS + dig];
    if (!LAST){
      keys_out[pos] = key;
      idx_out[pos]  = id;
      unsigned dign = (key >> NEXTSHIFT) & ((1u << NEXTBITS) - 1u);
      atomicAdd(&ghn[(pos >> 9)*(1 << NEXTBITS) + dign], 1u);
    } else {
      idx_out[pos] = id;       // final sorted ids
      unsrt[id] = pos;
    }
    __syncthreads();
    if (r == 0){
      #pragma unroll
      for (int k = 0; k < BPT; ++k){
        int bin = t*BPT + k;
        unsigned a = shw[bin] + shw[BINS+bin] + shw[2*BINS+bin] + shw[3*BINS+bin];
        runv[bin] += a;
        shw[bin] = 0u; shw[BINS+bin] = 0u; shw[2*BINS+bin] = 0u; shw[3*BINS+bin] = 0u;
      }
      __syncthreads();
    }
  }
}

// ============ fused scan: in-block staging + warm-up chunked recurrence + ctx ====
// grid (CCH, 2). scan thread t: d = t>>4 (channel), s = t&15 (state).
// stage thread t: p4 = t>>2 (position in tile), w4 = t&3 (k-quarter worker).
// PKL/SBL rows padded to 17; weight tables padded (win stride 9, wdt/wB/wC
// stride 17) so lane-dependent k = w4*4+kk spreads banks (R6 fix).
__global__ __launch_bounds__(256) void k_scan_fused(
    const float* __restrict__ g, const float* __restrict__ sh,
    const unsigned* __restrict__ sidx,
    const float* __restrict__ inprojW, const float* __restrict__ inprojb,
    const float* __restrict__ m_inW, const float* __restrict__ m_dtW,
    const float* __restrict__ m_dtb, const float* __restrict__ m_BW,
    const float* __restrict__ m_CW,
    const float* __restrict__ Alog, const float* __restrict__ rope,
    const float* __restrict__ m_D, const float* __restrict__ m_outW,
    const float* __restrict__ mfwd, const float* __restrict__ mbwd,
    float* __restrict__ CTX, float* __restrict__ dout)
{
  __shared__ float wip[16], wipb[8], win[288], wdt[272], wdtb[16];
  __shared__ float wB[272], wC[272], wOW[128];
  __shared__ float gsAll[(LCH+WRM)*2];
  __shared__ float4 PKL[64*17];     // {dt, dt*xb, sz, xb} per (pos, d), pad 17
  __shared__ float2 SBL[64*17];     // {ba, ca} per (pos, s), pad 17
  __shared__ float ldsV[64*17];     // v per (pos, d), pad 17

  int c = blockIdx.x, dir = blockIdx.y;
  int t = threadIdx.x;
  int d = t >> 4, s = t & 15;
  int p4 = t >> 2, w4 = t & 3;

  if (t < 16) wip[t] = inprojW[t];
  if (t < 8)  wipb[t] = inprojb[t];
  win[(t>>3)*9 + (t&7)]  = m_inW[dir*256 + t];
  wdt[(t>>4)*17 + (t&15)] = m_dtW[dir*256 + t];
  wB[(t>>4)*17 + (t&15)]  = m_BW[dir*256 + t];
  wC[(t>>4)*17 + (t&15)]  = m_CW[dir*256 + t];
  if (t < 16) wdtb[t] = m_dtb[dir*16 + t];
  if (t < 128) wOW[t] = m_outW[dir*128 + t];

  float Ah = -__expf(Alog[dir*256 + t]) * 0.5f;
  float rp = rope[dir*256 + t];
  float Dd = m_D[dir*16 + d];
  bool fwd = (dir == 0);
  int warm = ((fwd && c == 0) || (!fwd && c == CCH-1)) ? 0 : WRM;
  int npos = LCH + warm;
  int T = npos >> 6, warmT = warm >> 6;
  int pos0 = fwd ? (c*LCH - warm) : (c*LCH);
  float h = (warm == 0) ? (fwd ? mfwd[t] : mbwd[t]) : 0.f;

  // gather (g, s) pairs for this block's range once (L2-resident)
  if (t < npos){
    unsigned u = sidx[pos0 + t];
    gsAll[t*2]   = g[u];
    gsAll[t*2+1] = sh[u];
  }
  __syncthreads();

  for (int j = 0; j < T; ++j){
    int lo = fwd ? (pos0 + j*64) : (pos0 + npos - (j+1)*64);
    int loff = lo - pos0;
    // ---- staging: 4 workers per position, conflict-free padded access ----
    {
      float gg = gsAll[(loff + p4)*2], ss = gsAll[(loff + p4)*2 + 1];
      float x[8];
      #pragma unroll
      for (int m = 0; m < 8; ++m)
        x[m] = fmaf(wip[m*2], gg, fmaf(wip[m*2+1], ss, wipb[m]));
      float xb16[16];
      #pragma unroll
      for (int k = 0; k < 16; ++k){
        float a = 0.f;
        #pragma unroll
        for (int m = 0; m < 8; ++m) a += win[k*9+m]*x[m];
        xb16[k] = a;
      }
      #pragma unroll
      for (int kk = 0; kk < 4; ++kk){
        int k = w4*4 + kk;
        float zz = 0.f;
        #pragma unroll
        for (int m = 0; m < 8; ++m) zz += win[(16+k)*9+m]*x[m];
        float u = wdtb[k], ba = 0.f, ca = 0.f;
        #pragma unroll
        for (int m = 0; m < 16; ++m){
          float xm = xb16[m];
          u  += wdt[k*17+m]*xm;
          ba += wB[k*17+m]*xm;
          ca += wC[k*17+m]*xm;
        }
        float dt = d_softplus(u);
        float sz = zz * d_sigmoid(zz);
        PKL[p4*17 + k] = make_float4(dt, dt*xb16[k], sz, xb16[k]);
        SBL[p4*17 + k] = make_float2(ba, ca);
      }
    }
    __syncthreads();
    // ---- scan 64 steps ----
    bool real = (j >= warmT);
    for (int mb = 0; mb < 16; ++mb){
      float yv[4];
      #pragma unroll
      for (int q = 0; q < 4; ++q){
        int m = mb*4 + q;
        int lm = fwd ? m : 63 - m;
        float4 dd = PKL[lm*17 + d];
        float2 sv = SBL[lm*17 + s];
        float dt = dd.x, dxb = dd.y;
        float xh = dt * Ah;
        float Ab = (1.f + xh) * fast_rcp(1.f - xh + 1e-8f);
        float ph = dt * rp;                   // |ph| small -> Taylor
        float p2 = ph * ph;
        float ccos = 1.f - p2*(0.5f - 0.041666668f*p2);
        float ssin = ph*(1.f - 0.16666667f*p2);
        float a = Ab * ccos;
        float b = -Ab * ssin;
        float hm = dpp_mov<0x121>(h);         // roll(h,1)
        h = fmaf(a, h, fmaf(b, hm, dxb * sv.x));
        if (real){
          float v = h * sv.y;
          v += dpp_mov<0xB1>(v);
          v += dpp_mov<0x4E>(v);
          v += dpp_mov<0x140>(v);
          v += dpp_mov<0x141>(v);             // full 16-lane sum
          yv[q] = fmaf(v, dd.z, Dd * dd.w);   // y*silu(z) + D*xb
        }
      }
      if (real && s < 4){
        float val = (s == 0) ? yv[0] : ((s == 1) ? yv[1] : ((s == 2) ? yv[2] : yv[3]));
        int p = fwd ? (mb*4 + s) : (63 - (mb*4 + s));
        ldsV[p*17 + d] = val;
      }
    }
    __syncthreads();                          // scan reads + ldsV writes done
    // ---- ctx projection: 64 pos x 8 outputs, coalesced store ----
    if (real){
      #pragma unroll
      for (int r = 0; r < 2; ++r){
        int oidx = r*256 + t;
        int pos = oidx >> 3, m = oidx & 7;
        float a = 0.f;
        #pragma unroll
        for (int k = 0; k < 16; ++k) a += wOW[m*16 + k]*ldsV[pos*17 + k];
        CTX[(size_t)dir*NTOT*8 + (size_t)(lo + pos)*8 + m] = a;
      }
    }
  }
  if ((fwd && c == CCH-1) || (!fwd && c == 0))
    dout[5*NTOT + dir*256 + t] = h;           // new_fwd / new_bwd
}

// ============ final: GRU + PEER per original element (CTX gather) ============
__global__ __launch_bounds__(256) void k_final(
    const float* __restrict__ g, const float* __restrict__ sh,
    const float* __restrict__ gru_state, const unsigned* __restrict__ unsrt,
    const float* __restrict__ CTX,
    const float* __restrict__ Wz, const float* __restrict__ bz,
    const float* __restrict__ Wr, const float* __restrict__ br,
    const float* __restrict__ Wh, const float* __restrict__ bh,
    const float* __restrict__ qW, const float* __restrict__ kA, const float* __restrict__ kB,
    const float* __restrict__ eW1, const float* __restrict__ eb1,
    const float* __restrict__ eW2, const float* __restrict__ eb2,
    float* __restrict__ dout)
{
  __shared__ float sWz[88], sWr[88], sWh[88], sbz[4], sbr[4], sbh[4];
  __shared__ float sqW[704], skA[192], skB[192];
  // expert tables TRANSPOSED: [u][e] stride 144 -> e spreads across banks
  __shared__ float sW1[2304], sb1[2304], sW2[2304], sb2[144];
  int t = threadIdx.x;
  for (int k = t; k < 88; k += 256){ sWz[k]=Wz[k]; sWr[k]=Wr[k]; sWh[k]=Wh[k]; }
  if (t < 4){ sbz[t]=bz[t]; sbr[t]=br[t]; sbh[t]=bh[t]; }
  for (int k = t; k < 704; k += 256) sqW[k]=qW[k];
  for (int k = t; k < 192; k += 256){ skA[k]=kA[k]; skB[k]=kB[k]; }
  for (int k = t; k < 2304; k += 256){
    int e = k >> 4, u = k & 15;
    sW1[u*144 + e] = eW1[k];
    sb1[u*144 + e] = eb1[k];
    sW2[u*144 + e] = eW2[k];
  }
  for (int k = t; k < 144; k += 256) sb2[k]=eb2[k];
  __syncthreads();
  int i = blockIdx.x*256 + t;
  float gi = g[i], si = sh[i];
  unsigned j = unsrt[i];
  float xin[22];
  xin[0] = gi; xin[1] = si;
  {
    const float4* c0 = (const float4*)(CTX + (size_t)j*8);
    const float4* c1 = (const float4*)(CTX + (size_t)NTOT*8 + (size_t)j*8);
    float4 a0 = c0[0], a1 = c0[1], b0 = c1[0], b1 = c1[1];
    xin[2]=a0.x; xin[3]=a0.y; xin[4]=a0.z; xin[5]=a0.w;
    xin[6]=a1.x; xin[7]=a1.y; xin[8]=a1.z; xin[9]=a1.w;
    xin[10]=b0.x; xin[11]=b0.y; xin[12]=b0.z; xin[13]=b0.w;
    xin[14]=b1.x; xin[15]=b1.y; xin[16]=b1.z; xin[17]=b1.w;
  }
  float h[4];
  #pragma unroll
  for (int k = 0; k < 4; ++k) h[k] = gru_state[i*4 + k];
  float zg[4], r[4];
  #pragma unroll
  for (int o = 0; o < 4; ++o){
    float az = sbz[o], ar = sbr[o];
    #pragma unroll
    for (int c = 0; c < 18; ++c){ az += sWz[o*22+c]*xin[c]; ar += sWr[o*22+c]*xin[c]; }
    #pragma unroll
    for (int c = 0; c < 4; ++c){ az += sWz[o*22+18+c]*h[c]; ar += sWr[o*22+18+c]*h[c]; }
    zg[o] = d_sigmoid(az);
    r[o]  = d_sigmoid(ar);
  }
  float ng[4];
  #pragma unroll
  for (int o = 0; o < 4; ++o){
    float ah = sbh[o];
    #pragma unroll
    for (int c = 0; c < 18; ++c) ah += sWh[o*22+c]*xin[c];
    #pragma unroll
    for (int c = 0; c < 4; ++c) ah += sWh[o*22+18+c]*(r[c]*h[c]);
    float ht = tanhf(ah);
    ng[o] = (1.f - zg[o])*h[o] + zg[o]*ht;
  }
  float pin[22];
  #pragma unroll
  for (int k = 0; k < 4; ++k) pin[k] = ng[k];
  #pragma unroll
  for (int m = 0; m < 16; ++m) pin[4+m] = xin[2+m];
  pin[20] = gi; pin[21] = si;
  float total = 0.f;
  #pragma unroll
  for (int hh = 0; hh < 4; ++hh){
    float qv[8];
    #pragma unroll
    for (int o = 0; o < 8; ++o){
      float a = 0.f;
      #pragma unroll
      for (int c = 0; c < 22; ++c) a += sqW[hh*176 + o*22 + c]*pin[c];
      qv[o] = a;
    }
    int ia = 0; float best = -1e30f;
    #pragma unroll
    for (int k = 0; k < 12; ++k){
      float sc = 0.f;
      #pragma unroll
      for (int m = 0; m < 4; ++m) sc += skA[hh*48 + k*4 + m]*qv[m];
      if (sc > best){ best = sc; ia = k; }
    }
    int ib = 0; best = -1e30f;
    #pragma unroll
    for (int k = 0; k < 12; ++k){
      float sc = 0.f;
      #pragma unroll
      for (int m = 0; m < 4; ++m) sc += skB[hh*48 + k*4 + m]*qv[4+m];
      if (sc > best){ best = sc; ib = k; }
    }
    int e = ia*12 + ib;
    float outv = sb2[e];
    #pragma unroll
    for (int u = 0; u < 16; ++u){
      float z1 = fmaxf(sW1[u*144+e]*gi + sb1[u*144+e], 0.f);
      outv += sW2[u*144+e]*z1;
    }
    total += outv;
  }
  total *= 0.25f;
  dout[i] = gi + 0.1f*total;
  #pragma unroll
  for (int k = 0; k < 4; ++k) dout[NTOT + i*4 + k] = ng[k];
}

extern "C" void kernel_launch(void* const* d_in, const int* in_sizes, int n_in,
                              void* d_out, int out_size, void* d_ws, size_t ws_size,
                              hipStream_t stream)
{
  const float* grad     = (const float*)d_in[0];
  const float* sharp    = (const float*)d_in[1];
  const float* gru_st   = (const float*)d_in[2];
  const float* mfwd     = (const float*)d_in[3];
  const float* mbwd     = (const float*)d_in[4];
  const float* inprojW  = (const float*)d_in[5];
  const float* inprojb  = (const float*)d_in[6];
  const float* m_inW    = (const float*)d_in[7];
  const float* m_dtW    = (const float*)d_in[8];
  const float* m_dtb    = (const float*)d_in[9];
  const float* m_BW     = (const float*)d_in[10];
  const float* m_CW     = (const float*)d_in[11];
  const float* m_Alog   = (const float*)d_in[12];
  const float* m_D      = (const float*)d_in[13];
  const float* m_rope   = (const float*)d_in[14];
  const float* m_outW   = (const float*)d_in[15];
  const float* gWz      = (const float*)d_in[16];
  const float* gbz      = (const float*)d_in[17];
  const float* gWr      = (const float*)d_in[18];
  const float* gbr      = (const float*)d_in[19];
  const float* gWh      = (const float*)d_in[20];
  const float* gbh      = (const float*)d_in[21];
  const float* peer_qW  = (const float*)d_in[22];
  const float* keysA    = (const float*)d_in[23];
  const float* keysB    = (const float*)d_in[24];
  const float* eW1      = (const float*)d_in[25];
  const float* eb1      = (const float*)d_in[26];
  const float* eW2      = (const float*)d_in[27];
  const float* eb2      = (const float*)d_in[28];
  float* out = (float*)d_out;

  char* base = (char*)d_ws;
  size_t off = 0;
  auto alloc = [&](size_t bytes)->void*{
    void* p = (void*)(base + off);
    off = (off + bytes + 255) & ~(size_t)255;
    return p;
  };
  unsigned* keys0 = (unsigned*)alloc((size_t)NTOT*4);
  unsigned* keys1 = (unsigned*)alloc((size_t)NTOT*4);
  unsigned* idx0  = (unsigned*)alloc((size_t)NTOT*4);
  unsigned* idx1  = (unsigned*)alloc((size_t)NTOT*4);
  unsigned* sidx  = (unsigned*)alloc((size_t)NTOT*4);
  unsigned* unsrt = (unsigned*)alloc((size_t)NTOT*4);
  unsigned* gh0   = (unsigned*)alloc((size_t)NB*2048*4);
  unsigned* gh1   = (unsigned*)alloc((size_t)NB*2048*4);
  unsigned* gh2   = (unsigned*)alloc((size_t)NB*1024*4);
  float* CTX  = (float*)alloc((size_t)2*NTOT*8*4);   // 4 MB

  k_hist0<<<NB, 256, 0, stream>>>(grad, gh0, gh1, gh2);
  // pass 0: bits [0,11)  -> keys1/idx1, builds gh1
  k_scat<0,11,11,11,0><<<NB, 256, 0, stream>>>(grad, (const unsigned*)0, (const unsigned*)0,
      keys1, idx1, gh0, gh1, (unsigned*)0);
  // pass 1: bits [11,22) -> keys0/idx0, builds gh2
  k_scat<11,11,22,10,0><<<NB, 256, 0, stream>>>(grad, keys1, idx1,
      keys0, idx0, gh1, gh2, (unsigned*)0);
  // pass 2: bits [22,32) -> sidx + unsrt
  k_scat<22,10,0,1,1><<<NB, 256, 0, stream>>>(grad, keys0, idx0,
      (unsigned*)0, sidx, gh2, (unsigned*)0, unsrt);

  k_scan_fused<<<dim3(CCH, 2), 256, 0, stream>>>(grad, sharp, sidx,
      inprojW, inprojb, m_inW, m_dtW, m_dtb, m_BW, m_CW,
      m_Alog, m_rope, m_D, m_outW, mfwd, mbwd, CTX, out);
  k_final<<<NTOT/256, 256, 0, stream>>>(grad, sharp, gru_st, unsrt, CTX,
      gWz, gbz, gWr, gbr, gWh, gbh, peer_qW, keysA, keysB, eW1, eb1, eW2, eb2, out);
}

// Round 8
// 244.427 us; speedup vs baseline: 1.2532x; 1.2532x over previous
//
#include <hip/hip_runtime.h>
#include <math.h>

#define NTOT 65536
#define LCH 256
#define WRM 64
#define CCH 256          // NTOT / LCH
#define NB 128           // sort blocks
#define EPB 512          // elements per sort block

__device__ __forceinline__ float d_softplus(float x){
  return fmaxf(x, 0.f) + __logf(1.f + __expf(-fabsf(x)));
}
__device__ __forceinline__ float d_sigmoid(float x){
  return 1.f / (1.f + __expf(-x));
}
__device__ __forceinline__ float fast_rcp(float x){
  return __builtin_amdgcn_rcpf(x);
}
template<int CTRL>
__device__ __forceinline__ float dpp_mov(float x){
  return __int_as_float(__builtin_amdgcn_update_dpp(0, __float_as_int(x), CTRL, 0xF, 0xF, true));
}
// DPP ctrls: 0xB1 quad_perm xor1, 0x4E quad_perm xor2, 0x121 row_ror:1,
// 0x140 row_mirror, 0x141 row_half_mirror.

__device__ __forceinline__ unsigned block_incl_scan(unsigned v, unsigned* buf, int t){
  buf[t] = v; __syncthreads();
  #pragma unroll
  for (int off = 1; off < 256; off <<= 1){
    unsigned u = (t >= off) ? buf[t-off] : 0u;
    __syncthreads();
    buf[t] += u;
    __syncthreads();
  }
  unsigned r = buf[t];
  __syncthreads();
  return r;
}

// ============ hist0: per-block hist of bits [7,15) + zero next hists ============
__global__ __launch_bounds__(256) void k_hist0(
    const float* __restrict__ g,
    unsigned* __restrict__ gh0, unsigned* __restrict__ gh1, unsigned* __restrict__ gh2)
{
  __shared__ unsigned h[256];
  int t = threadIdx.x, blk = blockIdx.x;
  h[t] = 0u;
  __syncthreads();
  #pragma unroll
  for (int r = 0; r < 2; ++r){
    int i = blk*EPB + r*256 + t;
    unsigned key = __float_as_uint(g[i]) & 0x7fffffffu;
    atomicAdd(&h[(key >> 7) & 255u], 1u);
  }
  __syncthreads();
  gh0[blk*256 + t] = h[t];
  int z = blk*256 + t;
  gh1[z] = 0u; gh2[z] = 0u;
}

// ============ scatter pass: redundant global prefix + stable ballot scatter ======
// 8-bit digits at SHIFT; builds next pass's per-destination-block hist on the fly.
// Sort is exact on bits [7,31) of the |g| key; ties below that are index-stable
// (reorders only genuine near-ties; see R8 error analysis).
template<int FIRST, int SHIFT, int NEXTSHIFT, int LAST>
__global__ __launch_bounds__(256) void k_scatter(
    const float* __restrict__ gsrc,
    const unsigned* __restrict__ keys_in, const unsigned* __restrict__ idx_in,
    unsigned* __restrict__ keys_out, unsigned* __restrict__ idx_out,
    const unsigned* __restrict__ ghist, unsigned* __restrict__ ghn,
    unsigned* __restrict__ unsrt)
{
  __shared__ unsigned runv[256], buf[256], shw[1024];
  int t = threadIdx.x, blk = blockIdx.x;
  int lane = t & 63, wv = t >> 6;
  unsigned tot = 0u, myoff = 0u;
  for (int b = 0; b < NB; ++b){
    unsigned v = ghist[b*256 + t];
    if (b < blk) myoff += v;
    tot += v;
  }
  unsigned incl = block_incl_scan(tot, buf, t);
  runv[t] = (incl - tot) + myoff;
  shw[t] = 0u; shw[256+t] = 0u; shw[512+t] = 0u; shw[768+t] = 0u;
  __syncthreads();
  #pragma unroll
  for (int r = 0; r < 2; ++r){
    int i = blk*EPB + r*256 + t;
    unsigned key = FIRST ? (__float_as_uint(gsrc[i]) & 0x7fffffffu) : keys_in[i];
    unsigned id  = FIRST ? (unsigned)i : idx_in[i];
    unsigned dig = (key >> SHIFT) & 255u;
    unsigned long long m = ~0ull;
    #pragma unroll
    for (int b = 0; b < 8; ++b){
      unsigned long long bb = __ballot((dig >> b) & 1u);
      m &= ((dig >> b) & 1u) ? bb : ~bb;
    }
    unsigned rank = (unsigned)__popcll(m & ((1ull << lane) - 1ull));
    unsigned cnt  = (unsigned)__popcll(m);
    if (rank == 0) shw[wv*256 + dig] = cnt;
    __syncthreads();
    unsigned pos = runv[dig] + rank;
    for (int w2 = 0; w2 < wv; ++w2) pos += shw[w2*256 + dig];
    if (!LAST){
      keys_out[pos] = key;
      idx_out[pos]  = id;
      unsigned dign = (key >> NEXTSHIFT) & 255u;
      atomicAdd(&ghn[(pos >> 9)*256 + dign], 1u);
    } else {
      idx_out[pos] = id;       // final sorted ids
      unsrt[id] = pos;
    }
    __syncthreads();
    runv[t] += shw[t] + shw[256+t] + shw[512+t] + shw[768+t];
    shw[t] = 0u; shw[256+t] = 0u; shw[512+t] = 0u; shw[768+t] = 0u;
    __syncthreads();
  }
}

// ============ fused scan: in-block staging + warm-up chunked recurrence + ctx ====
// grid (CCH, 2). scan thread t: d = t>>4 (channel), s = t&15 (state).
// stage thread t: p4 = t>>2 (position in tile), w4 = t&3 (k-quarter worker).
// PKL/SBL rows padded to 17; weight tables padded (win stride 9, wdt/wB/wC
// stride 17) so lane-dependent k = w4*4+kk spreads banks (R6 fix).
__global__ __launch_bounds__(256) void k_scan_fused(
    const float* __restrict__ g, const float* __restrict__ sh,
    const unsigned* __restrict__ sidx,
    const float* __restrict__ inprojW, const float* __restrict__ inprojb,
    const float* __restrict__ m_inW, const float* __restrict__ m_dtW,
    const float* __restrict__ m_dtb, const float* __restrict__ m_BW,
    const float* __restrict__ m_CW,
    const float* __restrict__ Alog, const float* __restrict__ rope,
    const float* __restrict__ m_D, const float* __restrict__ m_outW,
    const float* __restrict__ mfwd, const float* __restrict__ mbwd,
    float* __restrict__ CTX, float* __restrict__ dout)
{
  __shared__ float wip[16], wipb[8], win[288], wdt[272], wdtb[16];
  __shared__ float wB[272], wC[272], wOW[128];
  __shared__ float gsAll[(LCH+WRM)*2];
  __shared__ float4 PKL[64*17];     // {dt, dt*xb, sz, xb} per (pos, d), pad 17
  __shared__ float2 SBL[64*17];     // {ba, ca} per (pos, s), pad 17
  __shared__ float ldsV[64*17];     // v per (pos, d), pad 17

  int c = blockIdx.x, dir = blockIdx.y;
  int t = threadIdx.x;
  int d = t >> 4, s = t & 15;
  int p4 = t >> 2, w4 = t & 3;

  if (t < 16) wip[t] = inprojW[t];
  if (t < 8)  wipb[t] = inprojb[t];
  win[(t>>3)*9 + (t&7)]  = m_inW[dir*256 + t];
  wdt[(t>>4)*17 + (t&15)] = m_dtW[dir*256 + t];
  wB[(t>>4)*17 + (t&15)]  = m_BW[dir*256 + t];
  wC[(t>>4)*17 + (t&15)]  = m_CW[dir*256 + t];
  if (t < 16) wdtb[t] = m_dtb[dir*16 + t];
  if (t < 128) wOW[t] = m_outW[dir*128 + t];

  float Ah = -__expf(Alog[dir*256 + t]) * 0.5f;
  float rp = rope[dir*256 + t];
  float Dd = m_D[dir*16 + d];
  bool fwd = (dir == 0);
  int warm = ((fwd && c == 0) || (!fwd && c == CCH-1)) ? 0 : WRM;
  int npos = LCH + warm;
  int T = npos >> 6, warmT = warm >> 6;
  int pos0 = fwd ? (c*LCH - warm) : (c*LCH);
  float h = (warm == 0) ? (fwd ? mfwd[t] : mbwd[t]) : 0.f;

  // gather (g, s) pairs for this block's range once (L2-resident)
  for (int k = t; k < npos; k += 256){
    unsigned u = sidx[pos0 + k];
    gsAll[k*2]   = g[u];
    gsAll[k*2+1] = sh[u];
  }
  __syncthreads();

  for (int j = 0; j < T; ++j){
    int lo = fwd ? (pos0 + j*64) : (pos0 + npos - (j+1)*64);
    int loff = lo - pos0;
    // ---- staging: 4 workers per position, conflict-free padded access ----
    {
      float gg = gsAll[(loff + p4)*2], ss = gsAll[(loff + p4)*2 + 1];
      float x[8];
      #pragma unroll
      for (int m = 0; m < 8; ++m)
        x[m] = fmaf(wip[m*2], gg, fmaf(wip[m*2+1], ss, wipb[m]));
      float xb16[16];
      #pragma unroll
      for (int k = 0; k < 16; ++k){
        float a = 0.f;
        #pragma unroll
        for (int m = 0; m < 8; ++m) a += win[k*9+m]*x[m];
        xb16[k] = a;
      }
      #pragma unroll
      for (int kk = 0; kk < 4; ++kk){
        int k = w4*4 + kk;
        float zz = 0.f;
        #pragma unroll
        for (int m = 0; m < 8; ++m) zz += win[(16+k)*9+m]*x[m];
        float u = wdtb[k], ba = 0.f, ca = 0.f;
        #pragma unroll
        for (int m = 0; m < 16; ++m){
          float xm = xb16[m];
          u  += wdt[k*17+m]*xm;
          ba += wB[k*17+m]*xm;
          ca += wC[k*17+m]*xm;
        }
        float dt = d_softplus(u);
        float sz = zz * d_sigmoid(zz);
        PKL[p4*17 + k] = make_float4(dt, dt*xb16[k], sz, xb16[k]);
        SBL[p4*17 + k] = make_float2(ba, ca);
      }
    }
    __syncthreads();
    // ---- scan 64 steps ----
    bool real = (j >= warmT);
    for (int mb = 0; mb < 16; ++mb){
      float yv[4];
      #pragma unroll
      for (int q = 0; q < 4; ++q){
        int m = mb*4 + q;
        int lm = fwd ? m : 63 - m;
        float4 dd = PKL[lm*17 + d];
        float2 sv = SBL[lm*17 + s];
        float dt = dd.x, dxb = dd.y;
        float xh = dt * Ah;
        float Ab = (1.f + xh) * fast_rcp(1.f - xh + 1e-8f);
        float ph = dt * rp;                   // |ph| small -> Taylor
        float p2 = ph * ph;
        float ccos = 1.f - p2*(0.5f - 0.041666668f*p2);
        float ssin = ph*(1.f - 0.16666667f*p2);
        float a = Ab * ccos;
        float b = -Ab * ssin;
        float hm = dpp_mov<0x121>(h);         // roll(h,1)
        h = fmaf(a, h, fmaf(b, hm, dxb * sv.x));
        if (real){
          float v = h * sv.y;
          v += dpp_mov<0xB1>(v);
          v += dpp_mov<0x4E>(v);
          v += dpp_mov<0x140>(v);
          v += dpp_mov<0x141>(v);             // full 16-lane sum
          yv[q] = fmaf(v, dd.z, Dd * dd.w);   // y*silu(z) + D*xb
        }
      }
      if (real && s < 4){
        float val = (s == 0) ? yv[0] : ((s == 1) ? yv[1] : ((s == 2) ? yv[2] : yv[3]));
        int p = fwd ? (mb*4 + s) : (63 - (mb*4 + s));
        ldsV[p*17 + d] = val;
      }
    }
    __syncthreads();                          // scan reads + ldsV writes done
    // ---- ctx projection: 64 pos x 8 outputs, coalesced store ----
    if (real){
      #pragma unroll
      for (int r = 0; r < 2; ++r){
        int oidx = r*256 + t;
        int pos = oidx >> 3, m = oidx & 7;
        float a = 0.f;
        #pragma unroll
        for (int k = 0; k < 16; ++k) a += wOW[m*16 + k]*ldsV[pos*17 + k];
        CTX[(size_t)dir*NTOT*8 + (size_t)(lo + pos)*8 + m] = a;
      }
    }
  }
  if ((fwd && c == CCH-1) || (!fwd && c == 0))
    dout[5*NTOT + dir*256 + t] = h;           // new_fwd / new_bwd
}

// ============ final: GRU + PEER per original element (CTX gather) ============
__global__ __launch_bounds__(256) void k_final(
    const float* __restrict__ g, const float* __restrict__ sh,
    const float* __restrict__ gru_state, const unsigned* __restrict__ unsrt,
    const float* __restrict__ CTX,
    const float* __restrict__ Wz, const float* __restrict__ bz,
    const float* __restrict__ Wr, const float* __restrict__ br,
    const float* __restrict__ Wh, const float* __restrict__ bh,
    const float* __restrict__ qW, const float* __restrict__ kA, const float* __restrict__ kB,
    const float* __restrict__ eW1, const float* __restrict__ eb1,
    const float* __restrict__ eW2, const float* __restrict__ eb2,
    float* __restrict__ dout)
{
  __shared__ float sWz[88], sWr[88], sWh[88], sbz[4], sbr[4], sbh[4];
  __shared__ float sqW[704], skA[192], skB[192];
  // expert tables TRANSPOSED: [u][e] stride 144 -> e spreads across banks
  __shared__ float sW1[2304], sb1[2304], sW2[2304], sb2[144];
  int t = threadIdx.x;
  for (int k = t; k < 88; k += 256){ sWz[k]=Wz[k]; sWr[k]=Wr[k]; sWh[k]=Wh[k]; }
  if (t < 4){ sbz[t]=bz[t]; sbr[t]=br[t]; sbh[t]=bh[t]; }
  for (int k = t; k < 704; k += 256) sqW[k]=qW[k];
  for (int k = t; k < 192; k += 256){ skA[k]=kA[k]; skB[k]=kB[k]; }
  for (int k = t; k < 2304; k += 256){
    int e = k >> 4, u = k & 15;
    sW1[u*144 + e] = eW1[k];
    sb1[u*144 + e] = eb1[k];
    sW2[u*144 + e] = eW2[k];
  }
  for (int k = t; k < 144; k += 256) sb2[k]=eb2[k];
  __syncthreads();
  int i = blockIdx.x*256 + t;
  float gi = g[i], si = sh[i];
  unsigned j = unsrt[i];
  float xin[22];
  xin[0] = gi; xin[1] = si;
  {
    const float4* c0 = (const float4*)(CTX + (size_t)j*8);
    const float4* c1 = (const float4*)(CTX + (size_t)NTOT*8 + (size_t)j*8);
    float4 a0 = c0[0], a1 = c0[1], b0 = c1[0], b1 = c1[1];
    xin[2]=a0.x; xin[3]=a0.y; xin[4]=a0.z; xin[5]=a0.w;
    xin[6]=a1.x; xin[7]=a1.y; xin[8]=a1.z; xin[9]=a1.w;
    xin[10]=b0.x; xin[11]=b0.y; xin[12]=b0.z; xin[13]=b0.w;
    xin[14]=b1.x; xin[15]=b1.y; xin[16]=b1.z; xin[17]=b1.w;
  }
  float h[4];
  #pragma unroll
  for (int k = 0; k < 4; ++k) h[k] = gru_state[i*4 + k];
  float zg[4], r[4];
  #pragma unroll
  for (int o = 0; o < 4; ++o){
    float az = sbz[o], ar = sbr[o];
    #pragma unroll
    for (int c = 0; c < 18; ++c){ az += sWz[o*22+c]*xin[c]; ar += sWr[o*22+c]*xin[c]; }
    #pragma unroll
    for (int c = 0; c < 4; ++c){ az += sWz[o*22+18+c]*h[c]; ar += sWr[o*22+18+c]*h[c]; }
    zg[o] = d_sigmoid(az);
    r[o]  = d_sigmoid(ar);
  }
  float ng[4];
  #pragma unroll
  for (int o = 0; o < 4; ++o){
    float ah = sbh[o];
    #pragma unroll
    for (int c = 0; c < 18; ++c) ah += sWh[o*22+c]*xin[c];
    #pragma unroll
    for (int c = 0; c < 4; ++c) ah += sWh[o*22+18+c]*(r[c]*h[c]);
    float ht = tanhf(ah);
    ng[o] = (1.f - zg[o])*h[o] + zg[o]*ht;
  }
  float pin[22];
  #pragma unroll
  for (int k = 0; k < 4; ++k) pin[k] = ng[k];
  #pragma unroll
  for (int m = 0; m < 16; ++m) pin[4+m] = xin[2+m];
  pin[20] = gi; pin[21] = si;
  float total = 0.f;
  #pragma unroll
  for (int hh = 0; hh < 4; ++hh){
    float qv[8];
    #pragma unroll
    for (int o = 0; o < 8; ++o){
      float a = 0.f;
      #pragma unroll
      for (int c = 0; c < 22; ++c) a += sqW[hh*176 + o*22 + c]*pin[c];
      qv[o] = a;
    }
    int ia = 0; float best = -1e30f;
    #pragma unroll
    for (int k = 0; k < 12; ++k){
      float sc = 0.f;
      #pragma unroll
      for (int m = 0; m < 4; ++m) sc += skA[hh*48 + k*4 + m]*qv[m];
      if (sc > best){ best = sc; ia = k; }
    }
    int ib = 0; best = -1e30f;
    #pragma unroll
    for (int k = 0; k < 12; ++k){
      float sc = 0.f;
      #pragma unroll
      for (int m = 0; m < 4; ++m) sc += skB[hh*48 + k*4 + m]*qv[4+m];
      if (sc > best){ best = sc; ib = k; }
    }
    int e = ia*12 + ib;
    float outv = sb2[e];
    #pragma unroll
    for (int u = 0; u < 16; ++u){
      float z1 = fmaxf(sW1[u*144+e]*gi + sb1[u*144+e], 0.f);
      outv += sW2[u*144+e]*z1;
    }
    total += outv;
  }
  total *= 0.25f;
  dout[i] = gi + 0.1f*total;
  #pragma unroll
  for (int k = 0; k < 4; ++k) dout[NTOT + i*4 + k] = ng[k];
}

extern "C" void kernel_launch(void* const* d_in, const int* in_sizes, int n_in,
                              void* d_out, int out_size, void* d_ws, size_t ws_size,
                              hipStream_t stream)
{
  const float* grad     = (const float*)d_in[0];
  const float* sharp    = (const float*)d_in[1];
  const float* gru_st   = (const float*)d_in[2];
  const float* mfwd     = (const float*)d_in[3];
  const float* mbwd     = (const float*)d_in[4];
  const float* inprojW  = (const float*)d_in[5];
  const float* inprojb  = (const float*)d_in[6];
  const float* m_inW    = (const float*)d_in[7];
  const float* m_dtW    = (const float*)d_in[8];
  const float* m_dtb    = (const float*)d_in[9];
  const float* m_BW     = (const float*)d_in[10];
  const float* m_CW     = (const float*)d_in[11];
  const float* m_Alog   = (const float*)d_in[12];
  const float* m_D      = (const float*)d_in[13];
  const float* m_rope   = (const float*)d_in[14];
  const float* m_outW   = (const float*)d_in[15];
  const float* gWz      = (const float*)d_in[16];
  const float* gbz      = (const float*)d_in[17];
  const float* gWr      = (const float*)d_in[18];
  const float* gbr      = (const float*)d_in[19];
  const float* gWh      = (const float*)d_in[20];
  const float* gbh      = (const float*)d_in[21];
  const float* peer_qW  = (const float*)d_in[22];
  const float* keysA    = (const float*)d_in[23];
  const float* keysB    = (const float*)d_in[24];
  const float* eW1      = (const float*)d_in[25];
  const float* eb1      = (const float*)d_in[26];
  const float* eW2      = (const float*)d_in[27];
  const float* eb2      = (const float*)d_in[28];
  float* out = (float*)d_out;

  char* base = (char*)d_ws;
  size_t off = 0;
  auto alloc = [&](size_t bytes)->void*{
    void* p = (void*)(base + off);
    off = (off + bytes + 255) & ~(size_t)255;
    return p;
  };
  unsigned* keys0 = (unsigned*)alloc((size_t)NTOT*4);
  unsigned* keys1 = (unsigned*)alloc((size_t)NTOT*4);
  unsigned* idx0  = (unsigned*)alloc((size_t)NTOT*4);
  unsigned* idx1  = (unsigned*)alloc((size_t)NTOT*4);
  unsigned* sidx  = (unsigned*)alloc((size_t)NTOT*4);
  unsigned* unsrt = (unsigned*)alloc((size_t)NTOT*4);
  unsigned* gh0   = (unsigned*)alloc((size_t)NB*256*4);
  unsigned* gh1   = (unsigned*)alloc((size_t)NB*256*4);
  unsigned* gh2   = (unsigned*)alloc((size_t)NB*256*4);
  float* CTX  = (float*)alloc((size_t)2*NTOT*8*4);   // 4 MB

  k_hist0<<<NB, 256, 0, stream>>>(grad, gh0, gh1, gh2);
  // pass 0: bits [7,15)  -> keys1/idx1, builds gh1
  k_scatter<1,7,15,0><<<NB, 256, 0, stream>>>(grad, (const unsigned*)0, (const unsigned*)0,
      keys1, idx1, gh0, gh1, (unsigned*)0);
  // pass 1: bits [15,23) -> keys0/idx0, builds gh2
  k_scatter<0,15,23,0><<<NB, 256, 0, stream>>>(grad, keys1, idx1,
      keys0, idx0, gh1, gh2, (unsigned*)0);
  // pass 2: bits [23,31) -> sidx + unsrt
  k_scatter<0,23,0,1><<<NB, 256, 0, stream>>>(grad, keys0, idx0,
      (unsigned*)0, sidx, gh2, (unsigned*)0, unsrt);

  k_scan_fused<<<dim3(CCH, 2), 256, 0, stream>>>(grad, sharp, sidx,
      inprojW, inprojb, m_inW, m_dtW, m_dtb, m_BW, m_CW,
      m_Alog, m_rope, m_D, m_outW, mfwd, mbwd, CTX, out);
  k_final<<<NTOT/256, 256, 0, stream>>>(grad, sharp, gru_st, unsrt, CTX,
      gWz, gbz, gWr, gbr, gWh, gbh, peer_qW, keysA, keysB, eW1, eb1, eW2, eb2, out);
}

// Round 10
// 231.046 us; speedup vs baseline: 1.3257x; 1.0579x over previous
//
#include <hip/hip_runtime.h>
#include <math.h>

#define NTOT 65536
#define LCH 128
#define WRM 64
#define TILE 32
#define CCH 512          // NTOT / LCH
#define NB 128           // sort blocks
#define EPB 512          // elements per sort block

__device__ __forceinline__ float d_softplus(float x){
  return fmaxf(x, 0.f) + __logf(1.f + __expf(-fabsf(x)));
}
__device__ __forceinline__ float d_sigmoid(float x){
  return 1.f / (1.f + __expf(-x));
}
__device__ __forceinline__ float fast_rcp(float x){
  return __builtin_amdgcn_rcpf(x);
}
template<int CTRL>
__device__ __forceinline__ float dpp_mov(float x){
  return __int_as_float(__builtin_amdgcn_update_dpp(0, __float_as_int(x), CTRL, 0xF, 0xF, true));
}
// DPP ctrls: 0xB1 quad_perm xor1, 0x4E quad_perm xor2, 0x121 row_ror:1,
// 0x140 row_mirror, 0x141 row_half_mirror.

__device__ __forceinline__ unsigned block_incl_scan(unsigned v, unsigned* buf, int t){
  buf[t] = v; __syncthreads();
  #pragma unroll
  for (int off = 1; off < 256; off <<= 1){
    unsigned u = (t >= off) ? buf[t-off] : 0u;
    __syncthreads();
    buf[t] += u;
    __syncthreads();
  }
  unsigned r = buf[t];
  __syncthreads();
  return r;
}

// ============ hist0: per-block hist of bits [7,15) + zero next hists ============
__global__ __launch_bounds__(256) void k_hist0(
    const float* __restrict__ g,
    unsigned* __restrict__ gh0, unsigned* __restrict__ gh1, unsigned* __restrict__ gh2)
{
  __shared__ unsigned h[256];
  int t = threadIdx.x, blk = blockIdx.x;
  h[t] = 0u;
  __syncthreads();
  #pragma unroll
  for (int r = 0; r < 2; ++r){
    int i = blk*EPB + r*256 + t;
    unsigned key = __float_as_uint(g[i]) & 0x7fffffffu;
    atomicAdd(&h[(key >> 7) & 255u], 1u);
  }
  __syncthreads();
  gh0[blk*256 + t] = h[t];
  int z = blk*256 + t;
  gh1[z] = 0u; gh2[z] = 0u;
}

// ============ scatter pass: redundant global prefix + stable ballot scatter ======
// 8-bit digits; exact sort on bits [7,31) of |g|, index-stable below.
template<int FIRST, int SHIFT, int NEXTSHIFT, int LAST>
__global__ __launch_bounds__(256) void k_scatter(
    const float* __restrict__ gsrc,
    const unsigned* __restrict__ keys_in, const unsigned* __restrict__ idx_in,
    unsigned* __restrict__ keys_out, unsigned* __restrict__ idx_out,
    const unsigned* __restrict__ ghist, unsigned* __restrict__ ghn)
{
  __shared__ unsigned runv[256], buf[256], shw[1024];
  int t = threadIdx.x, blk = blockIdx.x;
  int lane = t & 63, wv = t >> 6;
  unsigned tot = 0u, myoff = 0u;
  for (int b = 0; b < NB; ++b){
    unsigned v = ghist[b*256 + t];
    if (b < blk) myoff += v;
    tot += v;
  }
  unsigned incl = block_incl_scan(tot, buf, t);
  runv[t] = (incl - tot) + myoff;
  shw[t] = 0u; shw[256+t] = 0u; shw[512+t] = 0u; shw[768+t] = 0u;
  __syncthreads();
  #pragma unroll
  for (int r = 0; r < 2; ++r){
    int i = blk*EPB + r*256 + t;
    unsigned key = FIRST ? (__float_as_uint(gsrc[i]) & 0x7fffffffu) : keys_in[i];
    unsigned id  = FIRST ? (unsigned)i : idx_in[i];
    unsigned dig = (key >> SHIFT) & 255u;
    unsigned long long m = ~0ull;
    #pragma unroll
    for (int b = 0; b < 8; ++b){
      unsigned long long bb = __ballot((dig >> b) & 1u);
      m &= ((dig >> b) & 1u) ? bb : ~bb;
    }
    unsigned rank = (unsigned)__popcll(m & ((1ull << lane) - 1ull));
    unsigned cnt  = (unsigned)__popcll(m);
    if (rank == 0) shw[wv*256 + dig] = cnt;
    __syncthreads();
    unsigned pos = runv[dig] + rank;
    for (int w2 = 0; w2 < wv; ++w2) pos += shw[w2*256 + dig];
    if (!LAST){
      keys_out[pos] = key;
      idx_out[pos]  = id;
      unsigned dign = (key >> NEXTSHIFT) & 255u;
      atomicAdd(&ghn[(pos >> 9)*256 + dign], 1u);
    } else {
      idx_out[pos] = id;       // final sorted ids
    }
    __syncthreads();
    runv[t] += shw[t] + shw[256+t] + shw[512+t] + shw[768+t];
    shw[t] = 0u; shw[256+t] = 0u; shw[512+t] = 0u; shw[768+t] = 0u;
    __syncthreads();
  }
}

// ============ mega: both-direction scan + staging + ctx + GRU/PEER epilogue ======
// grid (CCH), 512 threads: waves 0-3 = fwd, waves 4-7 = bwd.
// Staged window gsAll covers offsets [0,256) = positions [c*LCH-WRM, c*LCH+LCH+WRM).
// fwd tiles span offsets [0, LCH+WRM); bwd tiles span [WRM, LCH+2*WRM) top-down.
// Real region (both) = offsets [WRM, WRM+LCH). Boundary halves reset h at warm end.
__global__ __launch_bounds__(512, 4) void k_mega(
    const float* __restrict__ g, const float* __restrict__ sh,
    const unsigned* __restrict__ sidx,
    const float* __restrict__ inprojW, const float* __restrict__ inprojb,
    const float* __restrict__ m_inW, const float* __restrict__ m_dtW,
    const float* __restrict__ m_dtb, const float* __restrict__ m_BW,
    const float* __restrict__ m_CW,
    const float* __restrict__ Alog, const float* __restrict__ rope,
    const float* __restrict__ m_D, const float* __restrict__ m_outW,
    const float* __restrict__ mfwd, const float* __restrict__ mbwd,
    const float* __restrict__ gru_state,
    const float* __restrict__ Wz, const float* __restrict__ bz,
    const float* __restrict__ Wr, const float* __restrict__ br,
    const float* __restrict__ Wh, const float* __restrict__ bh,
    const float* __restrict__ qW, const float* __restrict__ kA, const float* __restrict__ kB,
    const float* __restrict__ eW1, const float* __restrict__ eb1,
    const float* __restrict__ eW2, const float* __restrict__ eb2,
    float* __restrict__ dout)
{
  __shared__ float wip[16], wipb[8];
  __shared__ float win2[576], wdt2[544], wB2[544], wC2[544], wdtb2[32], wOW2[256];
  __shared__ float gsAll[512];          // 256 positions x (g,s)
  __shared__ float4 PKL[2*TILE*17];     // per dir: {dt, dt*xb, sz, xb} pad 17
  __shared__ float2 SBL[2*TILE*17];     // per dir: {ba, ca} pad 17
  __shared__ float ldsV[2*TILE*17];
  __shared__ float ctxT[2*LCH*8];       // fwd+bwd ctx for the 128 real positions
  __shared__ float sWz[88], sWr[88], sWh[88], sbz[4], sbr[4], sbh[4];
  __shared__ float sqW[704], skA[192], skB[192];
  __shared__ float hsum[LCH*4];

  int c = blockIdx.x;
  int t = threadIdx.x;
  int dir = t >> 8;          // 0 = fwd, 1 = bwd
  int tt = t & 255;
  int d = tt >> 4, s = tt & 15;
  int p8 = tt >> 3, w8 = tt & 7;

  if (t < 16) wip[t] = inprojW[t];
  if (t < 8)  wipb[t] = inprojb[t];
  { int dd = t >> 8, k = t & 255;
    win2[dd*288 + (k>>3)*9 + (k&7)]   = m_inW[t];
    wdt2[dd*272 + (k>>4)*17 + (k&15)] = m_dtW[t];
    wB2 [dd*272 + (k>>4)*17 + (k&15)] = m_BW[t];
    wC2 [dd*272 + (k>>4)*17 + (k&15)] = m_CW[t];
  }
  if (t < 32)  wdtb2[t] = m_dtb[t];
  if (t < 256) wOW2[t]  = m_outW[t];
  for (int k = t; k < 88; k += 512){ sWz[k]=Wz[k]; sWr[k]=Wr[k]; sWh[k]=Wh[k]; }
  if (t < 4){ sbz[t]=bz[t]; sbr[t]=br[t]; sbh[t]=bh[t]; }
  for (int k = t; k < 704; k += 512) sqW[k]=qW[k];
  for (int k = t; k < 192; k += 512){ skA[k]=kA[k]; skB[k]=kB[k]; }

  int base = c*LCH - WRM;
  for (int k = t; k < 256; k += 512){
    int p = base + k;
    p = p < 0 ? 0 : (p >= NTOT ? NTOT-1 : p);
    unsigned u = sidx[p];
    gsAll[k*2]   = g[u];
    gsAll[k*2+1] = sh[u];
  }

  float Ah = -__expf(Alog[dir*256 + tt]) * 0.5f;
  float rp = rope[dir*256 + tt];
  float Dd = m_D[dir*16 + d];
  bool fwd = (dir == 0);
  bool bnd = (fwd && c == 0) || (!fwd && c == CCH-1);
  float h = 0.f;
  const float* winp = &win2[dir*288];
  const float* wdtp = &wdt2[dir*272];
  const float* wBp  = &wB2[dir*272];
  const float* wCp  = &wC2[dir*272];
  __syncthreads();

  const int T = (LCH + WRM) / TILE;    // 6
  const int warmT = WRM / TILE;        // 2
  for (int j = 0; j < T; ++j){
    // R9 FIX: bwd region ends at offset LCH+2*WRM (=256), not LCH+WRM.
    int lo = fwd ? (base + j*TILE) : (base + (LCH + 2*WRM) - (j+1)*TILE);
    int loff = lo - base;
    // ---- staging: 8 workers per position, 32 positions per half ----
    {
      float gg = gsAll[(loff + p8)*2], ss = gsAll[(loff + p8)*2 + 1];
      float x[8];
      #pragma unroll
      for (int m = 0; m < 8; ++m)
        x[m] = fmaf(wip[m*2], gg, fmaf(wip[m*2+1], ss, wipb[m]));
      float xb16[16];
      #pragma unroll
      for (int k = 0; k < 16; ++k){
        float a = 0.f;
        #pragma unroll
        for (int m = 0; m < 8; ++m) a += winp[k*9+m]*x[m];
        xb16[k] = a;
      }
      #pragma unroll
      for (int kk = 0; kk < 2; ++kk){
        int k = w8*2 + kk;
        float zz = 0.f;
        #pragma unroll
        for (int m = 0; m < 8; ++m) zz += winp[(16+k)*9+m]*x[m];
        float u = wdtb2[dir*16+k], ba = 0.f, ca = 0.f;
        #pragma unroll
        for (int m = 0; m < 16; ++m){
          float xm = xb16[m];
          u  += wdtp[k*17+m]*xm;
          ba += wBp[k*17+m]*xm;
          ca += wCp[k*17+m]*xm;
        }
        float dt = d_softplus(u);
        float sz = zz * d_sigmoid(zz);
        PKL[(dir*TILE + p8)*17 + k] = make_float4(dt, dt*xb16[k], sz, xb16[k]);
        SBL[(dir*TILE + p8)*17 + k] = make_float2(ba, ca);
      }
    }
    __syncthreads();
    if (j == warmT && bnd) h = fwd ? mfwd[tt] : mbwd[tt];
    bool real = (j >= warmT);
    // ---- scan TILE steps ----
    for (int mb = 0; mb < TILE/4; ++mb){
      float yv[4];
      #pragma unroll
      for (int q = 0; q < 4; ++q){
        int m = mb*4 + q;
        int lm = fwd ? m : TILE-1 - m;
        float4 dd = PKL[(dir*TILE + lm)*17 + d];
        float2 sv = SBL[(dir*TILE + lm)*17 + s];
        float dt = dd.x, dxb = dd.y;
        float xh = dt * Ah;
        float Ab = (1.f + xh) * fast_rcp(1.f - xh + 1e-8f);
        float ph = dt * rp;                   // |ph| small -> Taylor
        float p2 = ph * ph;
        float ccos = 1.f - p2*(0.5f - 0.041666668f*p2);
        float ssin = ph*(1.f - 0.16666667f*p2);
        float a = Ab * ccos;
        float b = -Ab * ssin;
        float hm = dpp_mov<0x121>(h);         // roll(h,1)
        h = fmaf(a, h, fmaf(b, hm, dxb * sv.x));
        if (real){
          float v = h * sv.y;
          v += dpp_mov<0xB1>(v);
          v += dpp_mov<0x4E>(v);
          v += dpp_mov<0x140>(v);
          v += dpp_mov<0x141>(v);             // full 16-lane sum
          yv[q] = fmaf(v, dd.z, Dd * dd.w);   // y*silu(z) + D*xb
        }
      }
      if (real && s < 4){
        float val = (s == 0) ? yv[0] : ((s == 1) ? yv[1] : ((s == 2) ? yv[2] : yv[3]));
        int p = fwd ? (mb*4 + s) : (TILE-1 - (mb*4 + s));
        ldsV[(dir*TILE + p)*17 + d] = val;
      }
    }
    __syncthreads();
    // ---- ctx projection into LDS tile: 32 pos x 8 outputs per half ----
    if (real){
      int pos = tt >> 3, m = tt & 7;
      float a = 0.f;
      #pragma unroll
      for (int k = 0; k < 16; ++k) a += wOW2[dir*128 + m*16 + k]*ldsV[(dir*TILE + pos)*17 + k];
      ctxT[(dir*LCH + (lo - c*LCH + pos))*8 + m] = a;
    }
  }
  if (fwd && c == CCH-1)  dout[5*NTOT + tt] = h;         // new_fwd
  if (!fwd && c == 0)     dout[5*NTOT + 256 + tt] = h;   // new_bwd
  __syncthreads();

  // ---- epilogue: GRU + PEER, 4 head-threads per element ----
  {
    int elem = t >> 2, sub = t & 3;
    unsigned u = sidx[c*LCH + elem];
    float gi = gsAll[(WRM + elem)*2], si = gsAll[(WRM + elem)*2 + 1];
    float xin[22];
    xin[0] = gi; xin[1] = si;
    #pragma unroll
    for (int m = 0; m < 8; ++m){
      xin[2+m]  = ctxT[elem*8 + m];
      xin[10+m] = ctxT[(LCH + elem)*8 + m];
    }
    float hg[4];
    #pragma unroll
    for (int k = 0; k < 4; ++k) hg[k] = gru_state[u*4 + k];
    float zg[4], rg[4];
    #pragma unroll
    for (int o = 0; o < 4; ++o){
      float az = sbz[o], ar = sbr[o];
      #pragma unroll
      for (int cc = 0; cc < 18; ++cc){ az += sWz[o*22+cc]*xin[cc]; ar += sWr[o*22+cc]*xin[cc]; }
      #pragma unroll
      for (int cc = 0; cc < 4; ++cc){ az += sWz[o*22+18+cc]*hg[cc]; ar += sWr[o*22+18+cc]*hg[cc]; }
      zg[o] = d_sigmoid(az);
      rg[o] = d_sigmoid(ar);
    }
    float ng[4];
    #pragma unroll
    for (int o = 0; o < 4; ++o){
      float ah = sbh[o];
      #pragma unroll
      for (int cc = 0; cc < 18; ++cc) ah += sWh[o*22+cc]*xin[cc];
      #pragma unroll
      for (int cc = 0; cc < 4; ++cc) ah += sWh[o*22+18+cc]*(rg[cc]*hg[cc]);
      float ht = tanhf(ah);
      ng[o] = (1.f - zg[o])*hg[o] + zg[o]*ht;
    }
    if (sub == 0){
      #pragma unroll
      for (int k = 0; k < 4; ++k) dout[NTOT + u*4 + k] = ng[k];
    }
    float pin[22];
    #pragma unroll
    for (int k = 0; k < 4; ++k) pin[k] = ng[k];
    #pragma unroll
    for (int m = 0; m < 16; ++m) pin[4+m] = xin[2+m];
    pin[20] = gi; pin[21] = si;
    int hh = sub;
    float qv[8];
    #pragma unroll
    for (int o = 0; o < 8; ++o){
      float a = 0.f;
      #pragma unroll
      for (int cc = 0; cc < 22; ++cc) a += sqW[hh*176 + o*22 + cc]*pin[cc];
      qv[o] = a;
    }
    int ia = 0; float best = -1e30f;
    #pragma unroll
    for (int k = 0; k < 12; ++k){
      float sc = 0.f;
      #pragma unroll
      for (int m = 0; m < 4; ++m) sc += skA[hh*48 + k*4 + m]*qv[m];
      if (sc > best){ best = sc; ia = k; }
    }
    int ib = 0; best = -1e30f;
    #pragma unroll
    for (int k = 0; k < 12; ++k){
      float sc = 0.f;
      #pragma unroll
      for (int m = 0; m < 4; ++m) sc += skB[hh*48 + k*4 + m]*qv[4+m];
      if (sc > best){ best = sc; ib = k; }
    }
    int e = ia*12 + ib;
    float outv = eb2[e];
    #pragma unroll
    for (int u16 = 0; u16 < 16; ++u16){
      float z1 = fmaxf(eW1[e*16+u16]*gi + eb1[e*16+u16], 0.f);
      outv += eW2[e*16+u16]*z1;
    }
    hsum[elem*4 + sub] = outv;
  }
  __syncthreads();
  if (t < LCH){
    float total = (hsum[t*4] + hsum[t*4+1] + hsum[t*4+2] + hsum[t*4+3])*0.25f;
    unsigned u = sidx[c*LCH + t];
    float gi = gsAll[(WRM + t)*2];
    dout[u] = gi + 0.1f*total;
  }
}

extern "C" void kernel_launch(void* const* d_in, const int* in_sizes, int n_in,
                              void* d_out, int out_size, void* d_ws, size_t ws_size,
                              hipStream_t stream)
{
  const float* grad     = (const float*)d_in[0];
  const float* sharp    = (const float*)d_in[1];
  const float* gru_st   = (const float*)d_in[2];
  const float* mfwd     = (const float*)d_in[3];
  const float* mbwd     = (const float*)d_in[4];
  const float* inprojW  = (const float*)d_in[5];
  const float* inprojb  = (const float*)d_in[6];
  const float* m_inW    = (const float*)d_in[7];
  const float* m_dtW    = (const float*)d_in[8];
  const float* m_dtb    = (const float*)d_in[9];
  const float* m_BW     = (const float*)d_in[10];
  const float* m_CW     = (const float*)d_in[11];
  const float* m_Alog   = (const float*)d_in[12];
  const float* m_D      = (const float*)d_in[13];
  const float* m_rope   = (const float*)d_in[14];
  const float* m_outW   = (const float*)d_in[15];
  const float* gWz      = (const float*)d_in[16];
  const float* gbz      = (const float*)d_in[17];
  const float* gWr      = (const float*)d_in[18];
  const float* gbr      = (const float*)d_in[19];
  const float* gWh      = (const float*)d_in[20];
  const float* gbh      = (const float*)d_in[21];
  const float* peer_qW  = (const float*)d_in[22];
  const float* keysA    = (const float*)d_in[23];
  const float* keysB    = (const float*)d_in[24];
  const float* eW1      = (const float*)d_in[25];
  const float* eb1      = (const float*)d_in[26];
  const float* eW2      = (const float*)d_in[27];
  const float* eb2      = (const float*)d_in[28];
  float* out = (float*)d_out;

  char* base = (char*)d_ws;
  size_t off = 0;
  auto alloc = [&](size_t bytes)->void*{
    void* p = (void*)(base + off);
    off = (off + bytes + 255) & ~(size_t)255;
    return p;
  };
  unsigned* keys0 = (unsigned*)alloc((size_t)NTOT*4);
  unsigned* keys1 = (unsigned*)alloc((size_t)NTOT*4);
  unsigned* idx0  = (unsigned*)alloc((size_t)NTOT*4);
  unsigned* idx1  = (unsigned*)alloc((size_t)NTOT*4);
  unsigned* sidx  = (unsigned*)alloc((size_t)NTOT*4);
  unsigned* gh0   = (unsigned*)alloc((size_t)NB*256*4);
  unsigned* gh1   = (unsigned*)alloc((size_t)NB*256*4);
  unsigned* gh2   = (unsigned*)alloc((size_t)NB*256*4);

  k_hist0<<<NB, 256, 0, stream>>>(grad, gh0, gh1, gh2);
  // pass 0: bits [7,15)  -> keys1/idx1, builds gh1
  k_scatter<1,7,15,0><<<NB, 256, 0, stream>>>(grad, (const unsigned*)0, (const unsigned*)0,
      keys1, idx1, gh0, gh1);
  // pass 1: bits [15,23) -> keys0/idx0, builds gh2
  k_scatter<0,15,23,0><<<NB, 256, 0, stream>>>(grad, keys1, idx1,
      keys0, idx0, gh1, gh2);
  // pass 2: bits [23,31) -> sidx
  k_scatter<0,23,0,1><<<NB, 256, 0, stream>>>(grad, keys0, idx0,
      (unsigned*)0, sidx, gh2, (unsigned*)0);

  k_mega<<<CCH, 512, 0, stream>>>(grad, sharp, sidx,
      inprojW, inprojb, m_inW, m_dtW, m_dtb, m_BW, m_CW,
      m_Alog, m_rope, m_D, m_outW, mfwd, mbwd, gru_st,
      gWz, gbz, gWr, gbr, gWh, gbh, peer_qW, keysA, keysB,
      eW1, eb1, eW2, eb2, out);
}

// Round 11
// 217.807 us; speedup vs baseline: 1.4063x; 1.0608x over previous
//
#include <hip/hip_runtime.h>
#include <math.h>

#define NTOT 65536
#define LCH 128
#define WRM 32
#define TILE 32
#define CCH 512          // NTOT / LCH
#define NB 128           // sort blocks
#define EPB 512          // elements per sort block

__device__ __forceinline__ float d_softplus(float x){
  return fmaxf(x, 0.f) + __logf(1.f + __expf(-fabsf(x)));
}
__device__ __forceinline__ float d_sigmoid(float x){
  return 1.f / (1.f + __expf(-x));
}
__device__ __forceinline__ float fast_rcp(float x){
  return __builtin_amdgcn_rcpf(x);
}
template<int CTRL>
__device__ __forceinline__ float dpp_mov(float x){
  return __int_as_float(__builtin_amdgcn_update_dpp(0, __float_as_int(x), CTRL, 0xF, 0xF, true));
}
// DPP ctrls: 0xB1 quad_perm xor1, 0x4E quad_perm xor2, 0x121 row_ror:1,
// 0x140 row_mirror, 0x141 row_half_mirror.

__device__ __forceinline__ unsigned block_incl_scan(unsigned v, unsigned* buf, int t){
  buf[t] = v; __syncthreads();
  #pragma unroll
  for (int off = 1; off < 256; off <<= 1){
    unsigned u = (t >= off) ? buf[t-off] : 0u;
    __syncthreads();
    buf[t] += u;
    __syncthreads();
  }
  unsigned r = buf[t];
  __syncthreads();
  return r;
}

// ============ hist0: per-block hist of bits [7,15) + zero next hists ============
__global__ __launch_bounds__(256) void k_hist0(
    const float* __restrict__ g,
    unsigned* __restrict__ gh0, unsigned* __restrict__ gh1, unsigned* __restrict__ gh2)
{
  __shared__ unsigned h[256];
  int t = threadIdx.x, blk = blockIdx.x;
  h[t] = 0u;
  __syncthreads();
  #pragma unroll
  for (int r = 0; r < 2; ++r){
    int i = blk*EPB + r*256 + t;
    unsigned key = __float_as_uint(g[i]) & 0x7fffffffu;
    atomicAdd(&h[(key >> 7) & 255u], 1u);
  }
  __syncthreads();
  gh0[blk*256 + t] = h[t];
  int z = blk*256 + t;
  gh1[z] = 0u; gh2[z] = 0u;
}

// ============ scatter pass: redundant global prefix + stable ballot scatter ======
// 8-bit digits; exact sort on bits [7,31) of |g|, index-stable below.
template<int FIRST, int SHIFT, int NEXTSHIFT, int LAST>
__global__ __launch_bounds__(256) void k_scatter(
    const float* __restrict__ gsrc,
    const unsigned* __restrict__ keys_in, const unsigned* __restrict__ idx_in,
    unsigned* __restrict__ keys_out, unsigned* __restrict__ idx_out,
    const unsigned* __restrict__ ghist, unsigned* __restrict__ ghn)
{
  __shared__ unsigned runv[256], buf[256], shw[1024];
  int t = threadIdx.x, blk = blockIdx.x;
  int lane = t & 63, wv = t >> 6;
  unsigned tot = 0u, myoff = 0u;
  for (int b = 0; b < NB; ++b){
    unsigned v = ghist[b*256 + t];
    if (b < blk) myoff += v;
    tot += v;
  }
  unsigned incl = block_incl_scan(tot, buf, t);
  runv[t] = (incl - tot) + myoff;
  shw[t] = 0u; shw[256+t] = 0u; shw[512+t] = 0u; shw[768+t] = 0u;
  __syncthreads();
  #pragma unroll
  for (int r = 0; r < 2; ++r){
    int i = blk*EPB + r*256 + t;
    unsigned key = FIRST ? (__float_as_uint(gsrc[i]) & 0x7fffffffu) : keys_in[i];
    unsigned id  = FIRST ? (unsigned)i : idx_in[i];
    unsigned dig = (key >> SHIFT) & 255u;
    unsigned long long m = ~0ull;
    #pragma unroll
    for (int b = 0; b < 8; ++b){
      unsigned long long bb = __ballot((dig >> b) & 1u);
      m &= ((dig >> b) & 1u) ? bb : ~bb;
    }
    unsigned rank = (unsigned)__popcll(m & ((1ull << lane) - 1ull));
    unsigned cnt  = (unsigned)__popcll(m);
    if (rank == 0) shw[wv*256 + dig] = cnt;
    __syncthreads();
    unsigned pos = runv[dig] + rank;
    for (int w2 = 0; w2 < wv; ++w2) pos += shw[w2*256 + dig];
    if (!LAST){
      keys_out[pos] = key;
      idx_out[pos]  = id;
      unsigned dign = (key >> NEXTSHIFT) & 255u;
      atomicAdd(&ghn[(pos >> 9)*256 + dign], 1u);
    } else {
      idx_out[pos] = id;       // final sorted ids
    }
    __syncthreads();
    runv[t] += shw[t] + shw[256+t] + shw[512+t] + shw[768+t];
    shw[t] = 0u; shw[256+t] = 0u; shw[512+t] = 0u; shw[768+t] = 0u;
    __syncthreads();
  }
}

// ============ mega: both-direction scan + staging + ctx + GRU/PEER epilogue ======
// grid (CCH), 512 threads: waves 0-3 = fwd, waves 4-7 = bwd.
// Staged window gsAll covers offsets [0, LCH+2*WRM) = positions
// [c*LCH-WRM, c*LCH+LCH+WRM). fwd tiles span [0, LCH+WRM); bwd tiles span
// [WRM, LCH+2*WRM) top-down. Real region = [WRM, WRM+LCH).
// Staging is 2-phase: A) each of 8 workers computes its 2 xb entries -> xbL;
// B) workers read full xb16 from LDS and emit dt/ba/ca (kills 8x-redundant matvec).
__global__ __launch_bounds__(512, 4) void k_mega(
    const float* __restrict__ g, const float* __restrict__ sh,
    const unsigned* __restrict__ sidx,
    const float* __restrict__ inprojW, const float* __restrict__ inprojb,
    const float* __restrict__ m_inW, const float* __restrict__ m_dtW,
    const float* __restrict__ m_dtb, const float* __restrict__ m_BW,
    const float* __restrict__ m_CW,
    const float* __restrict__ Alog, const float* __restrict__ rope,
    const float* __restrict__ m_D, const float* __restrict__ m_outW,
    const float* __restrict__ mfwd, const float* __restrict__ mbwd,
    const float* __restrict__ gru_state,
    const float* __restrict__ Wz, const float* __restrict__ bz,
    const float* __restrict__ Wr, const float* __restrict__ br,
    const float* __restrict__ Wh, const float* __restrict__ bh,
    const float* __restrict__ qW, const float* __restrict__ kA, const float* __restrict__ kB,
    const float* __restrict__ eW1, const float* __restrict__ eb1,
    const float* __restrict__ eW2, const float* __restrict__ eb2,
    float* __restrict__ dout)
{
  __shared__ float wip[16], wipb[8];
  __shared__ float win2[576], wdt2[544], wB2[544], wC2[544], wdtb2[32], wOW2[256];
  __shared__ float gsAll[(LCH + 2*WRM)*2];
  __shared__ float4 PKL[2*TILE*17];     // per dir: {dt, dt*xb, sz, xb} pad 17
  __shared__ float2 SBL[2*TILE*17];     // per dir: {ba, ca} pad 17
  __shared__ float xbL[2*TILE*17];      // staging phase-A xb, pad 17
  __shared__ float ldsV[2*TILE*17];
  __shared__ float ctxT[2*LCH*8];       // fwd+bwd ctx for the 128 real positions
  __shared__ float sWz[88], sWr[88], sWh[88], sbz[4], sbr[4], sbh[4];
  __shared__ float sqW[704], skA[192], skB[192];
  __shared__ float hsum[LCH*4];

  int c = blockIdx.x;
  int t = threadIdx.x;
  int dir = t >> 8;          // 0 = fwd, 1 = bwd
  int tt = t & 255;
  int d = tt >> 4, s = tt & 15;
  int p8 = tt >> 3, w8 = tt & 7;

  if (t < 16) wip[t] = inprojW[t];
  if (t < 8)  wipb[t] = inprojb[t];
  { int dd = t >> 8, k = t & 255;
    win2[dd*288 + (k>>3)*9 + (k&7)]   = m_inW[t];
    wdt2[dd*272 + (k>>4)*17 + (k&15)] = m_dtW[t];
    wB2 [dd*272 + (k>>4)*17 + (k&15)] = m_BW[t];
    wC2 [dd*272 + (k>>4)*17 + (k&15)] = m_CW[t];
  }
  if (t < 32)  wdtb2[t] = m_dtb[t];
  if (t < 256) wOW2[t]  = m_outW[t];
  for (int k = t; k < 88; k += 512){ sWz[k]=Wz[k]; sWr[k]=Wr[k]; sWh[k]=Wh[k]; }
  if (t < 4){ sbz[t]=bz[t]; sbr[t]=br[t]; sbh[t]=bh[t]; }
  for (int k = t; k < 704; k += 512) sqW[k]=qW[k];
  for (int k = t; k < 192; k += 512){ skA[k]=kA[k]; skB[k]=kB[k]; }

  int base = c*LCH - WRM;
  for (int k = t; k < LCH + 2*WRM; k += 512){
    int p = base + k;
    p = p < 0 ? 0 : (p >= NTOT ? NTOT-1 : p);
    unsigned u = sidx[p];
    gsAll[k*2]   = g[u];
    gsAll[k*2+1] = sh[u];
  }

  float Ah = -__expf(Alog[dir*256 + tt]) * 0.5f;
  float rp = rope[dir*256 + tt];
  float Dd = m_D[dir*16 + d];
  bool fwd = (dir == 0);
  bool bnd = (fwd && c == 0) || (!fwd && c == CCH-1);
  float h = 0.f;
  const float* winp = &win2[dir*288];
  const float* wdtp = &wdt2[dir*272];
  const float* wBp  = &wB2[dir*272];
  const float* wCp  = &wC2[dir*272];
  __syncthreads();

  const int T = (LCH + WRM) / TILE;    // 5
  const int warmT = WRM / TILE;        // 1
  for (int j = 0; j < T; ++j){
    int lo = fwd ? (base + j*TILE) : (base + (LCH + 2*WRM) - (j+1)*TILE);
    int loff = lo - base;
    // ---- staging phase A: own 2 xb entries + z (kept in reg) ----
    float zreg[2];
    {
      float gg = gsAll[(loff + p8)*2], ss = gsAll[(loff + p8)*2 + 1];
      float x[8];
      #pragma unroll
      for (int m = 0; m < 8; ++m)
        x[m] = fmaf(wip[m*2], gg, fmaf(wip[m*2+1], ss, wipb[m]));
      #pragma unroll
      for (int kk = 0; kk < 2; ++kk){
        int k = w8*2 + kk;
        float a = 0.f, zz = 0.f;
        #pragma unroll
        for (int m = 0; m < 8; ++m){
          a  += winp[k*9+m]*x[m];
          zz += winp[(16+k)*9+m]*x[m];
        }
        xbL[(dir*TILE + p8)*17 + k] = a;
        zreg[kk] = zz;
      }
    }
    __syncthreads();
    // ---- staging phase B: read xb16, emit dt/ba/ca/sz ----
    {
      float xb16[16];
      #pragma unroll
      for (int m = 0; m < 16; ++m) xb16[m] = xbL[(dir*TILE + p8)*17 + m];
      #pragma unroll
      for (int kk = 0; kk < 2; ++kk){
        int k = w8*2 + kk;
        float u = wdtb2[dir*16+k], ba = 0.f, ca = 0.f;
        #pragma unroll
        for (int m = 0; m < 16; ++m){
          float xm = xb16[m];
          u  += wdtp[k*17+m]*xm;
          ba += wBp[k*17+m]*xm;
          ca += wCp[k*17+m]*xm;
        }
        float dt = d_softplus(u);
        float zz = zreg[kk];
        float sz = zz * d_sigmoid(zz);
        PKL[(dir*TILE + p8)*17 + k] = make_float4(dt, dt*xb16[k], sz, xb16[k]);
        SBL[(dir*TILE + p8)*17 + k] = make_float2(ba, ca);
      }
    }
    __syncthreads();
    if (j == warmT && bnd) h = fwd ? mfwd[tt] : mbwd[tt];
    bool real = (j >= warmT);
    // ---- scan TILE steps ----
    for (int mb = 0; mb < TILE/4; ++mb){
      float yv[4];
      #pragma unroll
      for (int q = 0; q < 4; ++q){
        int m = mb*4 + q;
        int lm = fwd ? m : TILE-1 - m;
        float4 dd = PKL[(dir*TILE + lm)*17 + d];
        float2 sv = SBL[(dir*TILE + lm)*17 + s];
        float dt = dd.x, dxb = dd.y;
        float xh = dt * Ah;
        float Ab = (1.f + xh) * fast_rcp(1.f - xh + 1e-8f);
        float ph = dt * rp;                   // |ph| small -> Taylor
        float p2 = ph * ph;
        float ccos = 1.f - p2*(0.5f - 0.041666668f*p2);
        float ssin = ph*(1.f - 0.16666667f*p2);
        float a = Ab * ccos;
        float b = -Ab * ssin;
        float hm = dpp_mov<0x121>(h);         // roll(h,1)
        h = fmaf(a, h, fmaf(b, hm, dxb * sv.x));
        if (real){
          float v = h * sv.y;
          v += dpp_mov<0xB1>(v);
          v += dpp_mov<0x4E>(v);
          v += dpp_mov<0x140>(v);
          v += dpp_mov<0x141>(v);             // full 16-lane sum
          yv[q] = fmaf(v, dd.z, Dd * dd.w);   // y*silu(z) + D*xb
        }
      }
      if (real && s < 4){
        float val = (s == 0) ? yv[0] : ((s == 1) ? yv[1] : ((s == 2) ? yv[2] : yv[3]));
        int p = fwd ? (mb*4 + s) : (TILE-1 - (mb*4 + s));
        ldsV[(dir*TILE + p)*17 + d] = val;
      }
    }
    __syncthreads();
    // ---- ctx projection into LDS tile: 32 pos x 8 outputs per half ----
    if (real){
      int pos = tt >> 3, m = tt & 7;
      float a = 0.f;
      #pragma unroll
      for (int k = 0; k < 16; ++k) a += wOW2[dir*128 + m*16 + k]*ldsV[(dir*TILE + pos)*17 + k];
      ctxT[(dir*LCH + (lo - c*LCH + pos))*8 + m] = a;
    }
  }
  if (fwd && c == CCH-1)  dout[5*NTOT + tt] = h;         // new_fwd
  if (!fwd && c == 0)     dout[5*NTOT + 256 + tt] = h;   // new_bwd
  __syncthreads();

  // ---- epilogue: GRU + PEER, 4 head-threads per element ----
  {
    int elem = t >> 2, sub = t & 3;
    unsigned u = sidx[c*LCH + elem];
    float gi = gsAll[(WRM + elem)*2], si = gsAll[(WRM + elem)*2 + 1];
    float xin[22];
    xin[0] = gi; xin[1] = si;
    #pragma unroll
    for (int m = 0; m < 8; ++m){
      xin[2+m]  = ctxT[elem*8 + m];
      xin[10+m] = ctxT[(LCH + elem)*8 + m];
    }
    float hg[4];
    #pragma unroll
    for (int k = 0; k < 4; ++k) hg[k] = gru_state[u*4 + k];
    float zg[4], rg[4];
    #pragma unroll
    for (int o = 0; o < 4; ++o){
      float az = sbz[o], ar = sbr[o];
      #pragma unroll
      for (int cc = 0; cc < 18; ++cc){ az += sWz[o*22+cc]*xin[cc]; ar += sWr[o*22+cc]*xin[cc]; }
      #pragma unroll
      for (int cc = 0; cc < 4; ++cc){ az += sWz[o*22+18+cc]*hg[cc]; ar += sWr[o*22+18+cc]*hg[cc]; }
      zg[o] = d_sigmoid(az);
      rg[o] = d_sigmoid(ar);
    }
    float ng[4];
    #pragma unroll
    for (int o = 0; o < 4; ++o){
      float ah = sbh[o];
      #pragma unroll
      for (int cc = 0; cc < 18; ++cc) ah += sWh[o*22+cc]*xin[cc];
      #pragma unroll
      for (int cc = 0; cc < 4; ++cc) ah += sWh[o*22+18+cc]*(rg[cc]*hg[cc]);
      float ht = tanhf(ah);
      ng[o] = (1.f - zg[o])*hg[o] + zg[o]*ht;
    }
    if (sub == 0){
      #pragma unroll
      for (int k = 0; k < 4; ++k) dout[NTOT + u*4 + k] = ng[k];
    }
    float pin[22];
    #pragma unroll
    for (int k = 0; k < 4; ++k) pin[k] = ng[k];
    #pragma unroll
    for (int m = 0; m < 16; ++m) pin[4+m] = xin[2+m];
    pin[20] = gi; pin[21] = si;
    int hh = sub;
    float qv[8];
    #pragma unroll
    for (int o = 0; o < 8; ++o){
      float a = 0.f;
      #pragma unroll
      for (int cc = 0; cc < 22; ++cc) a += sqW[hh*176 + o*22 + cc]*pin[cc];
      qv[o] = a;
    }
    int ia = 0; float best = -1e30f;
    #pragma unroll
    for (int k = 0; k < 12; ++k){
      float sc = 0.f;
      #pragma unroll
      for (int m = 0; m < 4; ++m) sc += skA[hh*48 + k*4 + m]*qv[m];
      if (sc > best){ best = sc; ia = k; }
    }
    int ib = 0; best = -1e30f;
    #pragma unroll
    for (int k = 0; k < 12; ++k){
      float sc = 0.f;
      #pragma unroll
      for (int m = 0; m < 4; ++m) sc += skB[hh*48 + k*4 + m]*qv[4+m];
      if (sc > best){ best = sc; ib = k; }
    }
    int e = ia*12 + ib;
    float outv = eb2[e];
    #pragma unroll
    for (int u16 = 0; u16 < 16; ++u16){
      float z1 = fmaxf(eW1[e*16+u16]*gi + eb1[e*16+u16], 0.f);
      outv += eW2[e*16+u16]*z1;
    }
    hsum[elem*4 + sub] = outv;
  }
  __syncthreads();
  if (t < LCH){
    float total = (hsum[t*4] + hsum[t*4+1] + hsum[t*4+2] + hsum[t*4+3])*0.25f;
    unsigned u = sidx[c*LCH + t];
    float gi = gsAll[(WRM + t)*2];
    dout[u] = gi + 0.1f*total;
  }
}

extern "C" void kernel_launch(void* const* d_in, const int* in_sizes, int n_in,
                              void* d_out, int out_size, void* d_ws, size_t ws_size,
                              hipStream_t stream)
{
  const float* grad     = (const float*)d_in[0];
  const float* sharp    = (const float*)d_in[1];
  const float* gru_st   = (const float*)d_in[2];
  const float* mfwd     = (const float*)d_in[3];
  const float* mbwd     = (const float*)d_in[4];
  const float* inprojW  = (const float*)d_in[5];
  const float* inprojb  = (const float*)d_in[6];
  const float* m_inW    = (const float*)d_in[7];
  const float* m_dtW    = (const float*)d_in[8];
  const float* m_dtb    = (const float*)d_in[9];
  const float* m_BW     = (const float*)d_in[10];
  const float* m_CW     = (const float*)d_in[11];
  const float* m_Alog   = (const float*)d_in[12];
  const float* m_D      = (const float*)d_in[13];
  const float* m_rope   = (const float*)d_in[14];
  const float* m_outW   = (const float*)d_in[15];
  const float* gWz      = (const float*)d_in[16];
  const float* gbz      = (const float*)d_in[17];
  const float* gWr      = (const float*)d_in[18];
  const float* gbr      = (const float*)d_in[19];
  const float* gWh      = (const float*)d_in[20];
  const float* gbh      = (const float*)d_in[21];
  const float* peer_qW  = (const float*)d_in[22];
  const float* keysA    = (const float*)d_in[23];
  const float* keysB    = (const float*)d_in[24];
  const float* eW1      = (const float*)d_in[25];
  const float* eb1      = (const float*)d_in[26];
  const float* eW2      = (const float*)d_in[27];
  const float* eb2      = (const float*)d_in[28];
  float* out = (float*)d_out;

  char* base = (char*)d_ws;
  size_t off = 0;
  auto alloc = [&](size_t bytes)->void*{
    void* p = (void*)(base + off);
    off = (off + bytes + 255) & ~(size_t)255;
    return p;
  };
  unsigned* keys0 = (unsigned*)alloc((size_t)NTOT*4);
  unsigned* keys1 = (unsigned*)alloc((size_t)NTOT*4);
  unsigned* idx0  = (unsigned*)alloc((size_t)NTOT*4);
  unsigned* idx1  = (unsigned*)alloc((size_t)NTOT*4);
  unsigned* sidx  = (unsigned*)alloc((size_t)NTOT*4);
  unsigned* gh0   = (unsigned*)alloc((size_t)NB*256*4);
  unsigned* gh1   = (unsigned*)alloc((size_t)NB*256*4);
  unsigned* gh2   = (unsigned*)alloc((size_t)NB*256*4);

  k_hist0<<<NB, 256, 0, stream>>>(grad, gh0, gh1, gh2);
  // pass 0: bits [7,15)  -> keys1/idx1, builds gh1
  k_scatter<1,7,15,0><<<NB, 256, 0, stream>>>(grad, (const unsigned*)0, (const unsigned*)0,
      keys1, idx1, gh0, gh1);
  // pass 1: bits [15,23) -> keys0/idx0, builds gh2
  k_scatter<0,15,23,0><<<NB, 256, 0, stream>>>(grad, keys1, idx1,
      keys0, idx0, gh1, gh2);
  // pass 2: bits [23,31) -> sidx
  k_scatter<0,23,0,1><<<NB, 256, 0, stream>>>(grad, keys0, idx0,
      (unsigned*)0, sidx, gh2, (unsigned*)0);

  k_mega<<<CCH, 512, 0, stream>>>(grad, sharp, sidx,
      inprojW, inprojb, m_inW, m_dtW, m_dtb, m_BW, m_CW,
      m_Alog, m_rope, m_D, m_outW, mfwd, mbwd, gru_st,
      gWz, gbz, gWr, gbr, gWh, gbh, peer_qW, keysA, keysB,
      eW1, eb1, eW2, eb2, out);
}